// Round 1
// 1398.271 us; speedup vs baseline: 1.0016x; 1.0016x over previous
//
#include <hip/hip_runtime.h>

#define EMBED 128
#define HEADS 4
#define HD 32
#define SEQL 4096
#define NB 4

typedef short bf16x8 __attribute__((ext_vector_type(8)));
typedef float f32x4 __attribute__((ext_vector_type(4)));

#define MFMA16(a, b, c) __builtin_amdgcn_mfma_f32_16x16x32_bf16(a, b, c, 0, 0, 0)

__device__ __forceinline__ unsigned short f2bf(float x) {
  unsigned int u = __float_as_uint(x);
  u += 0x7fffu + ((u >> 16) & 1u);   // RNE
  return (unsigned short)(u >> 16);
}

// ---------------- Kernel A: per-head projections (fp32 -> bf16) ----------------
// grid 3*1024, block 128. tz: 0=values->vp(Wv), 1=keys->kp(Wk), 2=query->qp(Wq)
// output layout: [n*HEADS+h][l][32] bf16
__global__ __launch_bounds__(128) void proj_kernel(
    const float* __restrict__ vin, const float* __restrict__ kin, const float* __restrict__ qin,
    const float* __restrict__ Wv, const float* __restrict__ Wk, const float* __restrict__ Wq,
    unsigned short* __restrict__ vp, unsigned short* __restrict__ kp, unsigned short* __restrict__ qp)
{
  __shared__ float Wl[32 * 33];
  __shared__ float xl[16 * 132];
  const int t = threadIdx.x;
  const int tz = blockIdx.x >> 10;
  const int blk = blockIdx.x & 1023;
  const long row0 = (long)blk * 16;

  const float* X = (tz == 0) ? vin : (tz == 1) ? kin : qin;
  const float* W = (tz == 0) ? Wv : (tz == 1) ? Wk : Wq;
  unsigned short* O = (tz == 0) ? vp : (tz == 1) ? kp : qp;

  #pragma unroll
  for (int i = 0; i < 8; ++i) {
    int idx = t + 128 * i;
    Wl[(idx >> 5) * 33 + (idx & 31)] = W[idx];
  }
  #pragma unroll
  for (int i = 0; i < 16; ++i) {
    int idx = t + 128 * i;
    xl[(idx >> 7) * 132 + (idx & 127)] = X[row0 * 128 + idx];
  }
  __syncthreads();

  const int h = t >> 5, e = t & 31;
  for (int r = 0; r < 16; ++r) {
    float acc = 0.f;
    #pragma unroll
    for (int d = 0; d < 32; ++d)
      acc += xl[r * 132 + h * 32 + d] * Wl[e * 33 + d];
    long row = row0 + r;
    int n = (int)(row >> 12);
    int l = (int)(row & 4095);
    O[(((long)(n * HEADS + h)) * SEQL + l) * HD + e] = f2bf(acc);
  }
}

// ---------------- Kernel B: fused attention ----------------
// grid 1024 (= 16 nh * 64 q-blocks), block 256 (4 waves, each owns 16 q-rows)
__global__ __launch_bounds__(256) void attn_kernel(
    const unsigned short* __restrict__ qp, const unsigned short* __restrict__ kp,
    const unsigned short* __restrict__ vp, const int* __restrict__ mask,
    float* __restrict__ attn, float* __restrict__ ctx)
{
  // chunk = 128 keys
  __shared__ unsigned short kl[128 * 40];   // K rows, stride 40 shorts (80B, 16B-pad)
  __shared__ unsigned short vl[32 * 136];   // V transposed [d][l], stride 136 shorts
  __shared__ unsigned short el[64 * 136];   // e (bf16) [qrow][kcol], stride 136
  __shared__ unsigned short ql[64 * 40];    // Q rows
  __shared__ __attribute__((aligned(16))) int ml[128];  // mask chunk (int4-readable)
  __shared__ float sinv[4][16];             // per-wave: inv row-sum for its 16 q-rows

  const int t = threadIdx.x;
  const int wave = t >> 6, lane = t & 63;
  const int quad = lane >> 4, c16 = lane & 15;
  const int nh = blockIdx.x >> 6, qb = blockIdx.x & 63;
  const int n = nh >> 2, h = nh & 3;
  const int q0 = qb * 64;
  const long base_nh = (long)nh * (SEQL * HD);
  const float SCALE = 0.08838834764831845f;  // 1/sqrt(128)
  const f32x4 zf = {0.f, 0.f, 0.f, 0.f};

  // stage Q tile (64 rows x 32): one float4 (8 bf16) per thread
  {
    float4 v = *(const float4*)(qp + base_nh + (long)q0 * HD + t * 8);
    int row = t >> 2, part = t & 3;
    *(float4*)(&ql[row * 40 + part * 8]) = v;
  }
  __syncthreads();

  const int q0w = wave * 16;
  const bf16x8 aq = *(const bf16x8*)(&ql[(q0w + c16) * 40 + quad * 8]);

  f32x4 o0 = zf, o1 = zf;
  float rs0 = 0.f, rs1 = 0.f, rs2 = 0.f, rs3 = 0.f;

  for (int ch = 0; ch < 32; ++ch) {
    __syncthreads();
    // stage K chunk: 128 rows x 32 bf16 = 512 float4
    {
      const float4* src = (const float4*)(kp + base_nh + (long)ch * (128 * HD));
      #pragma unroll
      for (int i = 0; i < 2; ++i) {
        int idx = t + 256 * i;
        float4 v = src[idx];
        int row = idx >> 2, part = idx & 3;
        *(float4*)(&kl[row * 40 + part * 8]) = v;
      }
    }
    // stage V chunk transposed: thread does half a row (16 d's)
    {
      int l = t >> 1, dbase = (t & 1) * 16;
      const uint4* vs = (const uint4*)(vp + base_nh + (long)ch * (128 * HD) + (long)l * HD + dbase);
      uint4 a0 = vs[0], a1 = vs[1];
      unsigned int uu[8] = {a0.x, a0.y, a0.z, a0.w, a1.x, a1.y, a1.z, a1.w};
      #pragma unroll
      for (int g = 0; g < 8; ++g) {
        int d = dbase + 2 * g;
        vl[d * 136 + l] = (unsigned short)(uu[g] & 0xffffu);
        vl[(d + 1) * 136 + l] = (unsigned short)(uu[g] >> 16);
      }
    }
    if (t < 128) ml[t] = mask[n * SEQL + ch * 128 + t];
    __syncthreads();

    // QK -> mask -> exp -> rowsum partials + e into LDS (A-layout for PV)
    #pragma unroll
    for (int kt = 0; kt < 8; ++kt) {
      bf16x8 bk = *(const bf16x8*)(&kl[(kt * 16 + c16) * 40 + quad * 8]);
      f32x4 c = MFMA16(aq, bk, zf);
      int col = kt * 16 + c16;
      int m = ml[col];
      float e0 = m ? __expf(c[0] * SCALE) : 0.f;
      float e1 = m ? __expf(c[1] * SCALE) : 0.f;
      float e2 = m ? __expf(c[2] * SCALE) : 0.f;
      float e3 = m ? __expf(c[3] * SCALE) : 0.f;
      rs0 += e0; rs1 += e1; rs2 += e2; rs3 += e3;
      int rbase = (q0w + quad * 4) * 136 + col;
      el[rbase + 0 * 136] = f2bf(e0);
      el[rbase + 1 * 136] = f2bf(e1);
      el[rbase + 2 * 136] = f2bf(e2);
      el[rbase + 3 * 136] = f2bf(e3);
    }
    // PV: O += P * V  (same-wave el write->read; compiler orders via lgkmcnt)
    #pragma unroll
    for (int ks = 0; ks < 4; ++ks) {
      bf16x8 ap = *(const bf16x8*)(&el[(q0w + c16) * 136 + ks * 32 + quad * 8]);
      bf16x8 bv0 = *(const bf16x8*)(&vl[c16 * 136 + ks * 32 + quad * 8]);
      bf16x8 bv1 = *(const bf16x8*)(&vl[(16 + c16) * 136 + ks * 32 + quad * 8]);
      o0 = MFMA16(ap, bv0, o0);
      o1 = MFMA16(ap, bv1, o1);
    }
  }

  // reduce row sums across the 16 column-lanes of each quad
  #pragma unroll
  for (int ms = 1; ms < 16; ms <<= 1) {
    rs0 += __shfl_xor(rs0, ms, 64);
    rs1 += __shfl_xor(rs1, ms, 64);
    rs2 += __shfl_xor(rs2, ms, 64);
    rs3 += __shfl_xor(rs3, ms, 64);
  }
  const float inv0 = 1.f / rs0, inv1 = 1.f / rs1, inv2 = 1.f / rs2, inv3 = 1.f / rs3;

  // publish per-q-row inv for pass 2 (lane c16==0 of each quad owns rows quad*4..+3)
  if (c16 == 0) {
    sinv[wave][quad * 4 + 0] = inv0;
    sinv[wave][quad * 4 + 1] = inv1;
    sinv[wave][quad * 4 + 2] = inv2;
    sinv[wave][quad * 4 + 3] = inv3;
  }

  // write ctx rows (normalized)
  {
    long rbase = (long)n * SEQL + q0 + q0w + quad * 4;
    float invs[4] = {inv0, inv1, inv2, inv3};
    #pragma unroll
    for (int r = 0; r < 4; ++r) {
      ctx[(rbase + r) * EMBED + h * 32 + c16] = o0[r] * invs[r];
      ctx[(rbase + r) * EMBED + h * 32 + 16 + c16] = o1[r] * invs[r];
    }
  }

  // pass 2: recompute scores with SWAPPED MFMA operands (row<->k, col<->q) so each
  // lane holds 4 consecutive k of one q-row -> one nontemporal dwordx4 store per kt.
  const float invq = sinv[wave][c16];                    // inv for this lane's q-row
  float* aprow = attn + ((long)nh * SEQL + (q0 + q0w + c16)) * (long)SEQL;

  for (int ch = 0; ch < 32; ++ch) {
    __syncthreads();
    {
      const float4* src = (const float4*)(kp + base_nh + (long)ch * (128 * HD));
      #pragma unroll
      for (int i = 0; i < 2; ++i) {
        int idx = t + 256 * i;
        float4 v = src[idx];
        int row = idx >> 2, part = idx & 3;
        *(float4*)(&kl[row * 40 + part * 8]) = v;
      }
    }
    if (t < 128) ml[t] = mask[n * SEQL + ch * 128 + t];
    __syncthreads();

    #pragma unroll
    for (int kt = 0; kt < 8; ++kt) {
      bf16x8 bk = *(const bf16x8*)(&kl[(kt * 16 + c16) * 40 + quad * 8]);
      f32x4 c = MFMA16(bk, aq, zf);                      // swapped: rows=k, cols=q
      const int4 mm = *(const int4*)(&ml[kt * 16 + quad * 4]);
      f32x4 w;
      w[0] = mm.x ? __expf(c[0] * SCALE) * invq : 0.f;
      w[1] = mm.y ? __expf(c[1] * SCALE) * invq : 0.f;
      w[2] = mm.z ? __expf(c[2] * SCALE) * invq : 0.f;
      w[3] = mm.w ? __expf(c[3] * SCALE) * invq : 0.f;
      __builtin_nontemporal_store(w, (f32x4*)(aprow + ch * 128 + kt * 16 + quad * 4));
    }
  }
}

// ---------------- Kernel C: out = ctx @ Wo^T + bo (fp32) ----------------
// grid 256 (64 rows each), block 256
__global__ __launch_bounds__(256) void outproj_kernel(
    const float* __restrict__ ctx, const float* __restrict__ Wo, const float* __restrict__ bo,
    float* __restrict__ out)
{
  __shared__ float Wol[128 * 132];
  __shared__ float ctxl[64 * 132];
  __shared__ float bol[128];
  const int t = threadIdx.x;
  const long row0 = (long)blockIdx.x * 64;

  #pragma unroll
  for (int i = 0; i < 64; ++i) {
    int idx = t + 256 * i;
    Wol[(idx >> 7) * 132 + (idx & 127)] = Wo[idx];
  }
  #pragma unroll
  for (int i = 0; i < 32; ++i) {
    int idx = t + 256 * i;
    ctxl[(idx >> 7) * 132 + (idx & 127)] = ctx[row0 * 128 + idx];
  }
  if (t < 128) bol[t] = bo[t];
  __syncthreads();

  const int r0 = (t >> 3) * 2;  // rows r0, r0+1
  const int e0 = t & 7;         // outputs e0 + 8k
  float acc0[16], acc1[16];
  #pragma unroll
  for (int k = 0; k < 16; ++k) { acc0[k] = bol[e0 + 8 * k]; acc1[k] = bol[e0 + 8 * k]; }

  for (int f = 0; f < 128; f += 4) {
    float4 x0 = *(const float4*)&ctxl[r0 * 132 + f];
    float4 x1 = *(const float4*)&ctxl[(r0 + 1) * 132 + f];
    #pragma unroll
    for (int k = 0; k < 16; ++k) {
      float4 w = *(const float4*)&Wol[(e0 + 8 * k) * 132 + f];
      acc0[k] += x0.x * w.x + x0.y * w.y + x0.z * w.z + x0.w * w.w;
      acc1[k] += x1.x * w.x + x1.y * w.y + x1.z * w.z + x1.w * w.w;
    }
  }
  #pragma unroll
  for (int k = 0; k < 16; ++k) {
    out[(row0 + r0) * 128 + e0 + 8 * k] = acc0[k];
    out[(row0 + r0 + 1) * 128 + e0 + 8 * k] = acc1[k];
  }
}

extern "C" void kernel_launch(void* const* d_in, const int* in_sizes, int n_in,
                              void* d_out, int out_size, void* d_ws, size_t ws_size,
                              hipStream_t stream) {
  const float* vin = (const float*)d_in[0];
  const float* kin = (const float*)d_in[1];
  const float* qin = (const float*)d_in[2];
  const int* mask = (const int*)d_in[3];
  const float* Wv = (const float*)d_in[4];
  const float* Wk = (const float*)d_in[5];
  const float* Wq = (const float*)d_in[6];
  const float* Wo = (const float*)d_in[7];
  const float* bo = (const float*)d_in[8];

  float* out = (float*)d_out;
  float* attn = out + (long)NB * SEQL * EMBED;  // +2097152

  char* ws = (char*)d_ws;
  unsigned short* vp = (unsigned short*)(ws);              // 4 MB bf16
  unsigned short* kp = (unsigned short*)(ws + (4l << 20)); // 4 MB
  unsigned short* qp = (unsigned short*)(ws + (8l << 20)); // 4 MB
  float* ctx = (float*)(ws + (12l << 20));                 // 8 MB fp32

  proj_kernel<<<3072, 128, 0, stream>>>(vin, kin, qin, Wv, Wk, Wq, vp, kp, qp);
  attn_kernel<<<1024, 256, 0, stream>>>(qp, kp, vp, mask, attn, ctx);
  outproj_kernel<<<256, 256, 0, stream>>>(ctx, Wo, bo, out);
}